// Round 1
// baseline (631.656 us; speedup 1.0000x reference)
//
#include <hip/hip_runtime.h>
#include <cstdint>
#include <cstddef>

#define D_DIM 128

typedef __attribute__((ext_vector_type(8))) __bf16 bf16x8;
typedef __attribute__((ext_vector_type(4))) float f32x4;

__device__ __forceinline__ unsigned short f2bf(float f) {
    unsigned u = __builtin_bit_cast(unsigned, f);
    u += 0x7FFFu + ((u >> 16) & 1u);   // round-to-nearest-even (no NaN in data)
    return (unsigned short)(u >> 16);
}
__device__ __forceinline__ float bf2f(unsigned short h) {
    unsigned u = ((unsigned)h) << 16;
    return __builtin_bit_cast(float, u);
}

// ---------------------------------------------------------------------------
// Prepass: fp32 -> bf16 conversion + squared norms of the bf16-rounded rows.
// One wave per TWO rows (float4 per lane = 16 B, the coalescing sweet spot).
// Lanes 0-31 handle row 2p, lanes 32-63 handle row 2p+1; shuffle-reduce
// stays within each 32-lane half (offsets <= 16).
// ---------------------------------------------------------------------------
__global__ __launch_bounds__(256) void prep_kernel(
    const float* __restrict__ x, const float* __restrict__ w,
    unsigned short* __restrict__ xb, unsigned short* __restrict__ wb,
    float* __restrict__ xsq, float* __restrict__ wsq,
    int n_rows_x, int n_rows_w)
{
    const int wave = threadIdx.x >> 6;
    const int lane = threadIdx.x & 63;
    const int half = lane >> 5;        // which row of the pair
    const int l32  = lane & 31;
    int row = blockIdx.x * 8 + wave * 2 + half;

    const float* src; unsigned short* dst; float* nrm; int r = row;
    if (row < n_rows_x) { src = x; dst = xb; nrm = xsq; }
    else {
        r = row - n_rows_x;
        if (r >= n_rows_w) return;     // never hits: grid is an exact fit
        src = w; dst = wb; nrm = wsq;
    }

    const float4 v = reinterpret_cast<const float4*>(src + (size_t)r * D_DIM)[l32];
    unsigned short b0 = f2bf(v.x), b1 = f2bf(v.y), b2 = f2bf(v.z), b3 = f2bf(v.w);
    float f0 = bf2f(b0), f1 = bf2f(b1), f2 = bf2f(b2), f3 = bf2f(b3);
    uint2 pack;
    pack.x = (unsigned)b0 | ((unsigned)b1 << 16);
    pack.y = (unsigned)b2 | ((unsigned)b3 << 16);
    reinterpret_cast<uint2*>(dst + (size_t)r * D_DIM)[l32] = pack;

    float s = f0 * f0 + f1 * f1 + f2 * f2 + f3 * f3;
    #pragma unroll
    for (int off = 16; off > 0; off >>= 1) s += __shfl_xor(s, off, 64);
    if (l32 == 0) nrm[r] = s;
}

// ---------------------------------------------------------------------------
// GEMM: out[n,c] = xsq[n] + wsq[c] - 2 * <x[n,:], w[c,:]>   (bf16 MFMA)
//
// LDS-free streaming design: K=128 fits in registers, w (256 KB bf16) is
// L2-resident, and x-tiles are served from the local XCD's L2 (each XCD is
// assigned a contiguous m-range, so all 8 c-tiles sharing an x-tile hit the
// same L2). No __syncthreads, no vmcnt(0) drain: each wave issues its 32
// fragment loads (16 B each, 64-B-segment coalesced) and streams the
// 128x128 fp32 output tile out with non-temporal dwordx4 stores.
//
// Operand swap: mfma(b, a) puts c-local in the D row index (quad*4+reg),
// m-local in the D col index (lane16) -> each lane's 4 acc regs are 4
// CONSECUTIVE output columns -> float4 stores.
// ---------------------------------------------------------------------------
__global__ __launch_bounds__(256, 2) void rbf_gemm(
    const unsigned short* __restrict__ xb, const unsigned short* __restrict__ wb,
    const float* __restrict__ xsq, const float* __restrict__ wsq,
    float* __restrict__ out, int C_total, int tiles_c, int tiles_m)
{
    // --- XCD-grouped tile mapping (hardware XCD = linear blockIdx % 8) ---
    int ty, tx;
    {
        const int bid = blockIdx.x;
        if ((tiles_m & 7) == 0) {
            const int xcd = bid & 7;
            const int i   = bid >> 3;
            const int iy  = i / tiles_c;
            ty = xcd * (tiles_m >> 3) + iy;   // contiguous m-range per XCD
            tx = i - iy * tiles_c;
        } else {
            ty = bid / tiles_c;
            tx = bid - ty * tiles_c;
        }
    }

    const int lane   = threadIdx.x & 63;
    const int wave   = threadIdx.x >> 6;
    const int lane16 = lane & 15;
    const int quad   = lane >> 4;
    const int wm = (wave & 1) * 64;
    const int wc = (wave >> 1) * 64;

    const long m0 = (long)ty * 128;
    const long c0 = (long)tx * 128;

    // Fragment base addresses. A-role and B-role layouts are identical:
    // lane holds row (lane&15) of the 16-row sub-tile, k = quad*8 + 0..7.
    const unsigned short* abase = xb + (size_t)(m0 + wm + lane16) * D_DIM + quad * 8;
    const unsigned short* bbase = wb + (size_t)(c0 + wc + lane16) * D_DIM + quad * 8;

    f32x4 acc[4][4];   // acc[ct][mt]
    #pragma unroll
    for (int i = 0; i < 4; ++i)
        #pragma unroll
        for (int j = 0; j < 4; ++j)
            acc[i][j] = (f32x4){0.f, 0.f, 0.f, 0.f};

    #pragma unroll
    for (int kk = 0; kk < D_DIM; kk += 32) {
        bf16x8 a[4], b[4];
        #pragma unroll
        for (int mt = 0; mt < 4; ++mt)
            a[mt] = *reinterpret_cast<const bf16x8*>(abase + (size_t)mt * 16 * D_DIM + kk);
        #pragma unroll
        for (int ct = 0; ct < 4; ++ct)
            b[ct] = *reinterpret_cast<const bf16x8*>(bbase + (size_t)ct * 16 * D_DIM + kk);
        #pragma unroll
        for (int ct = 0; ct < 4; ++ct)
            #pragma unroll
            for (int mt = 0; mt < 4; ++mt)
                acc[ct][mt] = __builtin_amdgcn_mfma_f32_16x16x32_bf16(
                    b[ct], a[mt], acc[ct][mt], 0, 0, 0);
    }

    // --- epilogue: D row = c-local = quad*4 + reg, D col = m-local = lane16 ---
    float xsv[4];
    #pragma unroll
    for (int mt = 0; mt < 4; ++mt)
        xsv[mt] = xsq[m0 + wm + mt * 16 + lane16];
    f32x4 wsv[4];
    #pragma unroll
    for (int ct = 0; ct < 4; ++ct)
        wsv[ct] = *reinterpret_cast<const f32x4*>(wsq + c0 + wc + ct * 16 + quad * 4);

    #pragma unroll
    for (int mt = 0; mt < 4; ++mt) {
        const long m = m0 + wm + mt * 16 + lane16;
        float* orow = out + m * (long)C_total + c0 + wc + quad * 4;
        #pragma unroll
        for (int ct = 0; ct < 4; ++ct) {
            f32x4 v;
            #pragma unroll
            for (int r = 0; r < 4; ++r)
                v[r] = xsv[mt] + wsv[ct][r] - 2.0f * acc[ct][mt][r];
            __builtin_nontemporal_store(v, reinterpret_cast<f32x4*>(orow + ct * 16));
        }
    }
}

extern "C" void kernel_launch(void* const* d_in, const int* in_sizes, int n_in,
                              void* d_out, int out_size, void* d_ws, size_t ws_size,
                              hipStream_t stream) {
    const float* x = (const float*)d_in[0];
    const float* w = (const float*)d_in[1];
    float* out = (float*)d_out;

    const int N = in_sizes[0] / D_DIM;   // 131072
    const int C = in_sizes[1] / D_DIM;   // 1024

    // workspace layout: xb bf16[N*128] | wb bf16[C*128] | xsq f32[N] | wsq f32[C]
    unsigned short* xb = (unsigned short*)d_ws;
    unsigned short* wb = xb + (size_t)N * D_DIM;
    float* xsq = (float*)(wb + (size_t)C * D_DIM);
    float* wsq = xsq + N;

    const int rows = N + C;
    prep_kernel<<<(rows + 7) / 8, 256, 0, stream>>>(x, w, xb, wb, xsq, wsq, N, C);

    const int tiles_m = N / 128;          // 1024
    const int tiles_c = C / 128;          // 8
    rbf_gemm<<<dim3(tiles_m * tiles_c), 256, 0, stream>>>(
        xb, wb, xsq, wsq, out, C, tiles_c, tiles_m);
}